// Round 13
// baseline (1710.252 us; speedup 1.0000x reference)
//
#include <hip/hip_runtime.h>
#include <hip/hip_fp16.h>
#include <stdint.h>

// LSTM policy rollout. Round-11 geometry (proven: 60 arch VGPR + 64 AGPR,
// 4 waves/SIMD, no spill) + wave-aligned rows: wave wv owns h-row wv fully
// (f,i,c rows: f,i in AGPR, c in LDS). After in-wave reduce, lane 0 has all
// three pre-activations -> local h update + immediate tagged publish.
// 2 block barriers/step -> 1 (z gather, double-buffered zsh).
// Sync: tagged {epoch,payload} u64 at MALL scope (relaxed agent atomics) +
// tagged LDS words for o / h-pairing / partials. No fences, no RMWs.

#define HID    4096
#define CTX    1024
#define NSTEPS 256
#define NBLK   256
#define TPB    1024
#define WAVES  16
#define HROWS  16
#define NCH    8           // column chunks of 512

typedef _Float16 h2 __attribute__((ext_vector_type(2)));

__device__ __forceinline__ float fdot2f(uint32_t a, uint32_t b, float c) {
#if __has_builtin(__builtin_amdgcn_fdot2)
  return __builtin_amdgcn_fdot2(__builtin_bit_cast(h2, a),
                                __builtin_bit_cast(h2, b), c, false);
#else
  h2 x = __builtin_bit_cast(h2, a), y = __builtin_bit_cast(h2, b);
  return c + (float)x[0]*(float)y[0] + (float)x[1]*(float)y[1];
#endif
}
__device__ __forceinline__ uint32_t pkf16(float x, float y) {
  h2 v; v[0] = (_Float16)x; v[1] = (_Float16)y;
  return __builtin_bit_cast(uint32_t, v);
}
__device__ __forceinline__ uint4 cvt8(const float* p) {
  return make_uint4(pkf16(p[0],p[1]), pkf16(p[2],p[3]),
                    pkf16(p[4],p[5]), pkf16(p[6],p[7]));
}
__device__ __forceinline__ float dot4(float acc, uint4 a, uint4 b) {
  acc = fdot2f(a.x, b.x, acc); acc = fdot2f(a.y, b.y, acc);
  acc = fdot2f(a.z, b.z, acc); acc = fdot2f(a.w, b.w, acc);
  return acc;
}
// AGPR residency (proven rounds 7-11).
__device__ __forceinline__ void agw(uint32_t &slot, uint32_t v) {
  asm volatile("v_accvgpr_write_b32 %0, %1" : "=a"(slot) : "v"(v));
}
__device__ __forceinline__ uint32_t agr(uint32_t slot) {
  uint32_t v;
  asm("v_accvgpr_read_b32 %0, %1" : "=v"(v) : "a"(slot));
  return v;
}
// MALL-coherent tagged exchange (global).
__device__ __forceinline__ void stT(uint64_t* p, uint32_t payload, uint32_t tag) {
  const uint64_t v = ((uint64_t)tag << 32) | (uint64_t)payload;
  __hip_atomic_store(p, v, __ATOMIC_RELAXED, __HIP_MEMORY_SCOPE_AGENT);
}
__device__ __forceinline__ uint64_t ldT(const uint64_t* p) {
  return __hip_atomic_load(p, __ATOMIC_RELAXED, __HIP_MEMORY_SCOPE_AGENT);
}
// LDS tagged exchange (workgroup scope).
__device__ __forceinline__ void stL(uint64_t* p, uint32_t payload, uint32_t tag) {
  const uint64_t v = ((uint64_t)tag << 32) | (uint64_t)payload;
  __hip_atomic_store(p, v, __ATOMIC_RELAXED, __HIP_MEMORY_SCOPE_WORKGROUP);
}
__device__ __forceinline__ uint32_t waitL(const uint64_t* p, uint32_t tag) {
  uint64_t v = __hip_atomic_load(p, __ATOMIC_RELAXED, __HIP_MEMORY_SCOPE_WORKGROUP);
  while ((uint32_t)(v >> 32) != tag) {
    __builtin_amdgcn_s_sleep(1);
    v = __hip_atomic_load(p, __ATOMIC_RELAXED, __HIP_MEMORY_SCOPE_WORKGROUP);
  }
  return (uint32_t)v;
}
// wave-uniform float -> SGPR
__device__ __forceinline__ float rfl(float x) {
  return __builtin_bit_cast(float,
      __builtin_amdgcn_readfirstlane(__builtin_bit_cast(int, x)));
}

__global__ __launch_bounds__(TPB)
void lstm(const float* __restrict__ ctx, const float* __restrict__ u,
          const float* __restrict__ l1w, const float* __restrict__ l1b,
          const float* __restrict__ Wf,  const float* __restrict__ Wfb,
          const float* __restrict__ Wi,  const float* __restrict__ Wib,
          const float* __restrict__ Wc,  const float* __restrict__ Wcb,
          const float* __restrict__ Wow, const float* __restrict__ Wob,
          uint64_t* __restrict__ hh0, uint64_t* __restrict__ hh1,
          uint64_t* __restrict__ part0, uint64_t* __restrict__ part1,
          float* __restrict__ out)
{
  __shared__ uint4    wlds[WAVES][HID/8];  // c-gate row per wave, 128 KB
  __shared__ uint4    zsh[2][HID/8];       // z f16x2, double-buffered, 16 KB
  __shared__ float    red[WAVES];
  __shared__ float    x0sh;
  __shared__ uint64_t osh;                 // {epoch, f32 o}
  __shared__ uint64_t ppl[WAVES];          // {epoch, f32 per-row partial}
  __shared__ uint64_t hxl[WAVES];          // {epoch, f32 h} odd->even pairing

  const int tid  = threadIdx.x;
  const int b    = blockIdx.x;
  const int wv   = tid >> 6;
  const int lane = tid & 63;

  {
    uint32_t* z0 = (uint32_t*)&zsh[0][0];
    for (int i = tid; i < HID/2; i += TPB) z0[i] = 0u;
    if (tid == 0) osh = 0ull;
    if (tid < WAVES) { ppl[tid] = 0ull; hxl[tid] = 0ull; }
  }

  // wave wv owns h-row (b*16 + wv): f,i rows -> AGPR; c row -> LDS
  const int hr = b*HROWS + wv;
  const float* rf = Wf + (size_t)hr*4097;
  const float* ri = Wi + (size_t)hr*4097;
  const float* rc = Wc + (size_t)hr*4097;

  // wave-uniform constants -> SGPRs
  const float bfv = rfl(Wfb[hr]), biv = rfl(Wib[hr]), bcv = rfl(Wcb[hr]);
  const float xfv = rfl(rf[HID]), xiv = rfl(ri[HID]), xcv = rfl(rc[HID]);
  const float wov = rfl(Wow[hr]);
  const float woxw = Wow[HID], wobv = Wob[0];

  uint32_t wreg[64];    // f row: [0..31], i row: [32..63]; AGPR-resident
  #pragma unroll
  for (int c = 0; c < NCH; ++c) {
    const int col = c*512 + lane*8;
    const uint4 vf = cvt8(rf + col);
    agw(wreg[c*4+0], vf.x); agw(wreg[c*4+1], vf.y);
    agw(wreg[c*4+2], vf.z); agw(wreg[c*4+3], vf.w);
    const uint4 vi = cvt8(ri + col);
    agw(wreg[32+c*4+0], vi.x); agw(wreg[32+c*4+1], vi.y);
    agw(wreg[32+c*4+2], vi.z); agw(wreg[32+c*4+3], vi.w);
    wlds[wv][c*64 + lane] = cvt8(rc + col);
  }

  // x0 = l1_w . context + l1_b (identical in every block); CTX == TPB
  {
    float p = l1w[tid] * ctx[tid];
    #pragma unroll
    for (int off = 32; off; off >>= 1) p += __shfl_down(p, off, 64);
    __syncthreads();                 // covers zsh[0]/osh/ppl/hxl init + wlds
    if (lane == 0) red[wv] = p;
    __syncthreads();
    if (tid == 0) {
      float s2 = 0.f;
      for (int w = 0; w < WAVES; ++w) s2 += red[w];
      x0sh = s2 + l1b[0];
    }
    __syncthreads();
  }
  float xcur = x0sh;
  float logp = 0.f;
  float ut = u[0];
  float cs = 0.f;                    // c-state of this wave's h-row (lane 0)

  for (int t = 0; t < NSTEPS; ++t) {
    // ---- wave 0: issue o-partial loads early (checked after dots) ----
    const uint64_t* prd = (t & 1) ? part0 : part1;
    uint64_t pv0 = 0, pv1 = 0, pv2 = 0, pv3 = 0;
    if (wv == 0 && t > 0) {
      pv0 = ldT(&prd[lane*4+0]); pv1 = ldT(&prd[lane*4+1]);
      pv2 = ldT(&prd[lane*4+2]); pv3 = ldT(&prd[lane*4+3]);
    }

    // ---- gate dots: f,i from AGPR, c from LDS ----
    float a0 = 0.f, a1 = 0.f, a2 = 0.f;
    const uint4* zb = zsh[t & 1];
    #pragma unroll
    for (int c = 0; c < NCH; ++c) {
      const uint4 zz = zb[c*64 + lane];
      const uint4 wl = wlds[wv][c*64 + lane];
      a0 = fdot2f(agr(wreg[c*4+0]), zz.x, a0);
      a0 = fdot2f(agr(wreg[c*4+1]), zz.y, a0);
      a0 = fdot2f(agr(wreg[c*4+2]), zz.z, a0);
      a0 = fdot2f(agr(wreg[c*4+3]), zz.w, a0);
      a1 = fdot2f(agr(wreg[32+c*4+0]), zz.x, a1);
      a1 = fdot2f(agr(wreg[32+c*4+1]), zz.y, a1);
      a1 = fdot2f(agr(wreg[32+c*4+2]), zz.z, a1);
      a1 = fdot2f(agr(wreg[32+c*4+3]), zz.w, a1);
      a2 = dot4(a2, wl, zz);
    }
    #pragma unroll
    for (int off = 32; off; off >>= 1) {
      a0 += __shfl_down(a0, off, 64);
      a1 += __shfl_down(a1, off, 64);
      a2 += __shfl_down(a2, off, 64);
    }

    // ---- wave 0: finish o, publish tagged to LDS ----
    if (wv == 0) {
      float ps = 0.f;
      if (t > 0) {
        const uint32_t tg = (uint32_t)t;
        while ((uint32_t)(pv0 >> 32) != tg) { __builtin_amdgcn_s_sleep(1); pv0 = ldT(&prd[lane*4+0]); }
        while ((uint32_t)(pv1 >> 32) != tg) { __builtin_amdgcn_s_sleep(1); pv1 = ldT(&prd[lane*4+1]); }
        while ((uint32_t)(pv2 >> 32) != tg) { __builtin_amdgcn_s_sleep(1); pv2 = ldT(&prd[lane*4+2]); }
        while ((uint32_t)(pv3 >> 32) != tg) { __builtin_amdgcn_s_sleep(1); pv3 = ldT(&prd[lane*4+3]); }
        const float q0 = __uint_as_float((uint32_t)pv0);
        const float q1 = __uint_as_float((uint32_t)pv1);
        const float q2 = __uint_as_float((uint32_t)pv2);
        const float q3 = __uint_as_float((uint32_t)pv3);
        ps = ((q0 + q1) + q2) + q3;
      }
      #pragma unroll
      for (int off = 32; off; off >>= 1) ps += __shfl_down(ps, off, 64);
      if (lane == 0) {
        const float opre = ps + woxw*xcur + wobv;
        const float o = 1.f / (1.f + expf(-opre));
        stL(&osh, __float_as_uint(o), (uint32_t)(t+1));
      }
    }

    // ---- each wave's lane 0: local h update + immediate publish ----
    uint64_t* hw = (t & 1) ? hh1 : hh0;
    uint64_t* pw = (t & 1) ? part1 : part0;
    if (lane == 0) {
      const float o = __uint_as_float(waitL(&osh, (uint32_t)(t+1)));
      const float s = (ut < o) ? 1.f : 0.f;
      const float pf = a0 + xfv*xcur + bfv;
      const float pi = a1 + xiv*xcur + biv;
      const float pc = a2 + xcv*xcur + bcv;
      const float ff = 1.f/(1.f+expf(-pf));
      const float ii = 1.f/(1.f+expf(-pi));
      const float cc = tanhf(pc);
      cs = ff*cs + ii*cc;
      const float hv = o*tanhf(cs);
      if (wv & 1) {
        stL(&hxl[wv], __float_as_uint(hv), (uint32_t)(t+1));
      } else {
        const float hv1 = __uint_as_float(waitL(&hxl[wv+1], (uint32_t)(t+1)));
        stT(&hw[b*8 + (wv>>1)], pkf16(hv, hv1), (uint32_t)(t+1));
      }
      stL(&ppl[wv], __float_as_uint(wov*hv), (uint32_t)(t+1));
      xcur = s;
      if (b == 0 && wv == 0) {
        logp += (s != 0.f) ? logf(o) : logf(1.f - o);
        out[t] = s;
      }
    }

    // ---- wave 0: collect 16 per-row partials, publish block partial ----
    if (wv == 0) {
      float v = 0.f;
      if (lane < WAVES) v = __uint_as_float(waitL(&ppl[lane], (uint32_t)(t+1)));
      v += __shfl_down(v, 8, 64);
      v += __shfl_down(v, 4, 64);
      v += __shfl_down(v, 2, 64);
      v += __shfl_down(v, 1, 64);
      if (lane == 0) stT(&pw[b], __float_as_uint(v), (uint32_t)(t+1));
    }

    if (t + 1 < NSTEPS) {
      // ---- gather z(t+1): poll tagged words (2 per thread) ----
      const uint64_t* hr2 = (t & 1) ? hh1 : hh0;
      const uint32_t tg = (uint32_t)(t+1);
      uint64_t v0 = ldT(&hr2[tid]);
      uint64_t v1 = ldT(&hr2[tid + TPB]);
      while ((uint32_t)(v0 >> 32) != tg) { __builtin_amdgcn_s_sleep(1); v0 = ldT(&hr2[tid]); }
      while ((uint32_t)(v1 >> 32) != tg) { __builtin_amdgcn_s_sleep(1); v1 = ldT(&hr2[tid + TPB]); }
      uint32_t* zn = (uint32_t*)&zsh[(t+1) & 1][0];
      zn[tid]       = (uint32_t)v0;
      zn[tid + TPB] = (uint32_t)v1;
      ut = u[t+1];
      __syncthreads();
    }
  }
  if (b == 0 && tid == 0) out[NSTEPS] = logp;
}

extern "C" void kernel_launch(void* const* d_in, const int* in_sizes, int n_in,
                              void* d_out, int out_size, void* d_ws, size_t ws_size,
                              hipStream_t stream) {
  const float* ctx = (const float*)d_in[0];
  const float* u   = (const float*)d_in[1];
  const float* l1w = (const float*)d_in[2];
  const float* l1b = (const float*)d_in[3];
  const float* Wf  = (const float*)d_in[4];
  const float* Wfb = (const float*)d_in[5];
  const float* Wi  = (const float*)d_in[6];
  const float* Wib = (const float*)d_in[7];
  const float* Wc  = (const float*)d_in[8];
  const float* Wcb = (const float*)d_in[9];
  const float* Wow = (const float*)d_in[10];
  const float* Wob = (const float*)d_in[11];
  float* out = (float*)d_out;

  char* ws = (char*)d_ws;
  uint64_t* part0 = (uint64_t*)(ws + 4096);            // 256*8B
  uint64_t* part1 = (uint64_t*)(ws + 8192);
  uint64_t* hh0   = (uint64_t*)(ws + 12288);           // 2048*8B = 16 KB
  uint64_t* hh1   = (uint64_t*)(ws + 12288 + 16384);
  // zero all tags each launch (epochs 1..256; 0 == invalid)
  (void)hipMemsetAsync(ws + 4096, 0, 40960, stream);

  lstm<<<NBLK, TPB, 0, stream>>>(ctx,u,l1w,l1b,Wf,Wfb,Wi,Wib,Wc,Wcb,Wow,Wob,
                                 hh0,hh1,part0,part1,out);
}

// Round 15
// 1028.566 us; speedup vs baseline: 1.6628x; 1.6628x over previous
//
#include <hip/hip_runtime.h>
#include <hip/hip_fp16.h>
#include <stdint.h>

// LSTM policy rollout — round-11 kernel (proven best: 1008 us, absmax 0).
// 256 blocks x 1024 threads, 1 block/CU. Weights: 2 rows/wave in AGPRs
// (inline-asm "a" class, unspillable; 64 slots) + 1 row/wave in LDS (128 KB).
// Cross-block exchange: h (f16x2) and o-partials published as {epoch,payload}
// uint64 via RELAXED agent-scope atomics (MALL-coherent; no fences, no RMWs,
// no buffer_inv anywhere in the loop). Consumers poll the tag of the exact
// word they need -> flag wait + data load fused into ONE MALL round trip.
// NOTE (r14): v_dot2_f32_f16 cannot source AGPRs -> v_accvgpr_read is required.

#define HID    4096
#define CTX    1024
#define NSTEPS 256
#define NBLK   256
#define TPB    1024
#define WAVES  16
#define HROWS  16
#define GROWS  48
#define RPW    3           // rows per wave (2 AGPR + 1 LDS)
#define NCH    8           // column chunks of 512

typedef _Float16 h2 __attribute__((ext_vector_type(2)));

__device__ __forceinline__ float fdot2f(uint32_t a, uint32_t b, float c) {
#if __has_builtin(__builtin_amdgcn_fdot2)
  return __builtin_amdgcn_fdot2(__builtin_bit_cast(h2, a),
                                __builtin_bit_cast(h2, b), c, false);
#else
  h2 x = __builtin_bit_cast(h2, a), y = __builtin_bit_cast(h2, b);
  return c + (float)x[0]*(float)y[0] + (float)x[1]*(float)y[1];
#endif
}
__device__ __forceinline__ uint32_t pkf16(float x, float y) {
  h2 v; v[0] = (_Float16)x; v[1] = (_Float16)y;
  return __builtin_bit_cast(uint32_t, v);
}
__device__ __forceinline__ uint4 cvt8(const float* p) {
  return make_uint4(pkf16(p[0],p[1]), pkf16(p[2],p[3]),
                    pkf16(p[4],p[5]), pkf16(p[6],p[7]));
}
__device__ __forceinline__ float dot4(float acc, uint4 a, uint4 b) {
  acc = fdot2f(a.x, b.x, acc); acc = fdot2f(a.y, b.y, acc);
  acc = fdot2f(a.z, b.z, acc); acc = fdot2f(a.w, b.w, acc);
  return acc;
}
// AGPR residency (proven rounds 7-11).
__device__ __forceinline__ void agw(uint32_t &slot, uint32_t v) {
  asm volatile("v_accvgpr_write_b32 %0, %1" : "=a"(slot) : "v"(v));
}
__device__ __forceinline__ uint32_t agr(uint32_t slot) {
  uint32_t v;
  asm("v_accvgpr_read_b32 %0, %1" : "=v"(v) : "a"(slot));
  return v;
}
// MALL-coherent tagged exchange (global).
__device__ __forceinline__ void stT(uint64_t* p, uint32_t payload, uint32_t tag) {
  const uint64_t v = ((uint64_t)tag << 32) | (uint64_t)payload;
  __hip_atomic_store(p, v, __ATOMIC_RELAXED, __HIP_MEMORY_SCOPE_AGENT);
}
__device__ __forceinline__ uint64_t ldT(const uint64_t* p) {
  return __hip_atomic_load(p, __ATOMIC_RELAXED, __HIP_MEMORY_SCOPE_AGENT);
}

__global__ __launch_bounds__(TPB)
void lstm(const float* __restrict__ ctx, const float* __restrict__ u,
          const float* __restrict__ l1w, const float* __restrict__ l1b,
          const float* __restrict__ Wf,  const float* __restrict__ Wfb,
          const float* __restrict__ Wi,  const float* __restrict__ Wib,
          const float* __restrict__ Wc,  const float* __restrict__ Wcb,
          const float* __restrict__ Wow, const float* __restrict__ Wob,
          uint64_t* __restrict__ hh0, uint64_t* __restrict__ hh1,
          uint64_t* __restrict__ part0, uint64_t* __restrict__ part1,
          float* __restrict__ out)
{
  __shared__ uint4 wlds[WAVES][HID/8];    // 1 LDS row per wave, 128 KB
  __shared__ uint4 zsh4[HID/8];           // z packed f16x2, 8 KB
  __shared__ float red[WAVES];
  __shared__ float pre[GROWS];
  __shared__ float cst[HROWS];
  __shared__ float bias[GROWS];
  __shared__ float wx[GROWS];             // column-4096 (x) weight per row
  __shared__ float x0sh, osh, ssh;

  const int tid  = threadIdx.x;
  const int b    = blockIdx.x;
  const int wv   = tid >> 6;
  const int lane = tid & 63;

  uint32_t* z32 = (uint32_t*)zsh4;
  for (int i = tid; i < HID/2; i += TPB) z32[i] = 0u;
  if (tid < HROWS) cst[tid] = 0.f;
  if (tid < GROWS) {
    int g = tid / HROWS, j = tid % HROWS;
    const float* bw = (g==0 ? Wfb : (g==1 ? Wib : Wcb));
    const float* gw = (g==0 ? Wf  : (g==1 ? Wi  : Wc ));
    bias[tid] = bw[b*HROWS + j];
    wx[tid]   = gw[(size_t)(b*HROWS + j)*4097 + 4096];
  }

  // per-row o-gate weight for this block's h rows (tid<16, wave 0)
  const float wolocal = (tid < HROWS) ? Wow[b*HROWS + tid] : 0.f;
  const float woxw = Wow[HID];
  const float wob0 = Wob[0];

  // load + convert this wave's 3 gate rows: 2 -> AGPRs, 1 -> LDS
  uint32_t wreg[64];    // fully unrolled access only; lives in AGPRs
  {
    const int fl0 = wv*RPW;
    const int g0 = (fl0+0)/HROWS, j0 = (fl0+0)%HROWS;
    const int g1 = (fl0+1)/HROWS, j1 = (fl0+1)%HROWS;
    const int g2 = (fl0+2)/HROWS, j2 = (fl0+2)%HROWS;
    const float* r0 = (g0==0?Wf:(g0==1?Wi:Wc)) + (size_t)(b*HROWS+j0)*4097;
    const float* r1 = (g1==0?Wf:(g1==1?Wi:Wc)) + (size_t)(b*HROWS+j1)*4097;
    const float* r2 = (g2==0?Wf:(g2==1?Wi:Wc)) + (size_t)(b*HROWS+j2)*4097;
    #pragma unroll
    for (int c = 0; c < NCH; ++c) {
      const int col = c*512 + lane*8;
      const uint4 va = cvt8(r0 + col);
      agw(wreg[c*8+0], va.x); agw(wreg[c*8+1], va.y);
      agw(wreg[c*8+2], va.z); agw(wreg[c*8+3], va.w);
      const uint4 vb = cvt8(r1 + col);
      agw(wreg[c*8+4], vb.x); agw(wreg[c*8+5], vb.y);
      agw(wreg[c*8+6], vb.z); agw(wreg[c*8+7], vb.w);
      wlds[wv][c*64 + lane] = cvt8(r2 + col);
    }
  }

  // x0 = l1_w . context + l1_b (identical in every block); CTX == TPB
  {
    float p = l1w[tid] * ctx[tid];
    #pragma unroll
    for (int off = 32; off; off >>= 1) p += __shfl_down(p, off, 64);
    __syncthreads();                 // covers zsh init + wlds + cst
    if (lane == 0) red[wv] = p;
    __syncthreads();
    if (tid == 0) {
      float ssum = 0.f;
      for (int w = 0; w < WAVES; ++w) ssum += red[w];
      x0sh = ssum + l1b[0];
    }
    __syncthreads();
  }
  float xcur = x0sh;
  float logp = 0.f;
  float ut = u[0];

  for (int t = 0; t < NSTEPS; ++t) {
    // ---- wave 0: issue o-partial loads early (checked after dots) ----
    const uint64_t* prd = (t & 1) ? part0 : part1;
    uint64_t pv0 = 0, pv1 = 0, pv2 = 0, pv3 = 0;
    if (wv == 0 && t > 0) {
      pv0 = ldT(&prd[lane*4+0]); pv1 = ldT(&prd[lane*4+1]);
      pv2 = ldT(&prd[lane*4+2]); pv3 = ldT(&prd[lane*4+3]);
    }

    // ---- f/i/c gate dots from resident weights (AGPR + LDS) ----
    float a0 = 0.f, a1 = 0.f, a2 = 0.f;
    #pragma unroll
    for (int c = 0; c < NCH; ++c) {
      const uint4 zz = zsh4[c*64 + lane];
      const uint4 wl = wlds[wv][c*64 + lane];
      a0 = fdot2f(agr(wreg[c*8+0]), zz.x, a0);
      a0 = fdot2f(agr(wreg[c*8+1]), zz.y, a0);
      a0 = fdot2f(agr(wreg[c*8+2]), zz.z, a0);
      a0 = fdot2f(agr(wreg[c*8+3]), zz.w, a0);
      a1 = fdot2f(agr(wreg[c*8+4]), zz.x, a1);
      a1 = fdot2f(agr(wreg[c*8+5]), zz.y, a1);
      a1 = fdot2f(agr(wreg[c*8+6]), zz.z, a1);
      a1 = fdot2f(agr(wreg[c*8+7]), zz.w, a1);
      a2 = dot4(a2, wl, zz);
    }
    #pragma unroll
    for (int off = 32; off; off >>= 1) {
      a0 += __shfl_down(a0, off, 64);
      a1 += __shfl_down(a1, off, 64);
      a2 += __shfl_down(a2, off, 64);
    }

    // ---- wave 0: finish o (fixed tree, bit-identical in every block) ----
    if (wv == 0) {
      float ps = 0.f;
      if (t > 0) {
        const uint32_t tg = (uint32_t)t;
        while ((uint32_t)(pv0 >> 32) != tg) { __builtin_amdgcn_s_sleep(1); pv0 = ldT(&prd[lane*4+0]); }
        while ((uint32_t)(pv1 >> 32) != tg) { __builtin_amdgcn_s_sleep(1); pv1 = ldT(&prd[lane*4+1]); }
        while ((uint32_t)(pv2 >> 32) != tg) { __builtin_amdgcn_s_sleep(1); pv2 = ldT(&prd[lane*4+2]); }
        while ((uint32_t)(pv3 >> 32) != tg) { __builtin_amdgcn_s_sleep(1); pv3 = ldT(&prd[lane*4+3]); }
        const float q0 = __uint_as_float((uint32_t)pv0);
        const float q1 = __uint_as_float((uint32_t)pv1);
        const float q2 = __uint_as_float((uint32_t)pv2);
        const float q3 = __uint_as_float((uint32_t)pv3);
        ps = ((q0 + q1) + q2) + q3;
      }
      #pragma unroll
      for (int off = 32; off; off >>= 1) ps += __shfl_down(ps, off, 64);
      if (lane == 0) {
        const float opre = ps + woxw*xcur + wob0;
        const float o = 1.f / (1.f + expf(-opre));
        osh = o;
        ssh = (ut < o) ? 1.f : 0.f;
      }
    }
    if (lane == 0) {
      const int fl = wv*RPW;
      pre[fl+0] = a0 + wx[fl+0]*xcur + bias[fl+0];
      pre[fl+1] = a1 + wx[fl+1]*xcur + bias[fl+1];
      pre[fl+2] = a2 + wx[fl+2]*xcur + bias[fl+2];
    }
    __syncthreads();   // pre[] + osh/ssh visible to all

    // ---- h update; wave 0 publishes tagged h + partial (epoch t+1) ----
    const float o = osh;
    const float s = ssh;
    uint64_t* hwH = (t & 1) ? hh1 : hh0;
    uint64_t* pwF = (t & 1) ? part1 : part0;
    float hv = 0.f;
    if (tid < HROWS) {
      const float ff = 1.f / (1.f + expf(-pre[tid]));
      const float ii = 1.f / (1.f + expf(-pre[HROWS+tid]));
      const float cc = tanhf(pre[2*HROWS+tid]);
      const float cn = ff*cst[tid] + ii*cc;
      cst[tid] = cn;
      hv = o * tanhf(cn);
    }
    if (tid < 64) {
      // partial o-dot over this block's 16 h values (deterministic tree)
      float pp = wolocal * hv;      // zero for lanes 16-63
      #pragma unroll
      for (int off = 8; off; off >>= 1) pp += __shfl_down(pp, off, 64);
      const float he = __shfl(hv, 2*(tid&7),   64);
      const float ho = __shfl(hv, 2*(tid&7)+1, 64);
      if (tid < 8) stT(&hwH[b*8 + tid], pkf16(he, ho), (uint32_t)(t+1));
      if (tid == 0) stT(&pwF[b], __float_as_uint(pp), (uint32_t)(t+1));
    }
    if (b == 0 && tid == 0) {
      logp += (s != 0.f) ? logf(o) : logf(1.f - o);
      out[t] = s;
    }
    xcur = s;

    if (t + 1 < NSTEPS) {
      // ---- gather z(t): poll the tagged words directly (one round trip) ----
      const uint64_t* hr2 = (t & 1) ? hh1 : hh0;
      const uint32_t tg = (uint32_t)(t+1);
      uint64_t v0 = ldT(&hr2[tid]);
      uint64_t v1 = ldT(&hr2[tid + TPB]);
      while ((uint32_t)(v0 >> 32) != tg) {
        __builtin_amdgcn_s_sleep(1); v0 = ldT(&hr2[tid]);
      }
      while ((uint32_t)(v1 >> 32) != tg) {
        __builtin_amdgcn_s_sleep(1); v1 = ldT(&hr2[tid + TPB]);
      }
      z32[tid]       = (uint32_t)v0;
      z32[tid + TPB] = (uint32_t)v1;
      ut = u[t+1];
      __syncthreads();
    }
  }
  if (b == 0 && tid == 0) out[NSTEPS] = logp;
}

extern "C" void kernel_launch(void* const* d_in, const int* in_sizes, int n_in,
                              void* d_out, int out_size, void* d_ws, size_t ws_size,
                              hipStream_t stream) {
  const float* ctx = (const float*)d_in[0];
  const float* u   = (const float*)d_in[1];
  const float* l1w = (const float*)d_in[2];
  const float* l1b = (const float*)d_in[3];
  const float* Wf  = (const float*)d_in[4];
  const float* Wfb = (const float*)d_in[5];
  const float* Wi  = (const float*)d_in[6];
  const float* Wib = (const float*)d_in[7];
  const float* Wc  = (const float*)d_in[8];
  const float* Wcb = (const float*)d_in[9];
  const float* Wow = (const float*)d_in[10];
  const float* Wob = (const float*)d_in[11];
  float* out = (float*)d_out;

  char* ws = (char*)d_ws;
  uint64_t* part0 = (uint64_t*)(ws + 4096);            // 256*8B
  uint64_t* part1 = (uint64_t*)(ws + 8192);
  uint64_t* hh0   = (uint64_t*)(ws + 12288);           // 2048*8B = 16 KB
  uint64_t* hh1   = (uint64_t*)(ws + 12288 + 16384);
  // zero all tags each launch (epochs 1..256; 0 == invalid)
  (void)hipMemsetAsync(ws + 4096, 0, 40960, stream);

  lstm<<<NBLK, TPB, 0, stream>>>(ctx,u,l1w,l1b,Wf,Wfb,Wi,Wib,Wc,Wcb,Wow,Wob,
                                 hh0,hh1,part0,part1,out);
}